// Round 1
// baseline (139.125 us; speedup 1.0000x reference)
//
#include <hip/hip_runtime.h>
#include <math.h>

#define NACC 29

__device__ __forceinline__ float4 qmul4(float4 a, float4 b) {
    return make_float4(
        a.w*b.x + a.x*b.w + a.y*b.z - a.z*b.y,
        a.w*b.y - a.x*b.z + a.y*b.w + a.z*b.x,
        a.w*b.z + a.x*b.y - a.y*b.x + a.z*b.w,
        a.w*b.w - a.x*b.x - a.y*b.y - a.z*b.z);
}

// rotate v=(0,1,0) by q_inv(q) = (-x,-y,-z,w), reference q_rot formula
__device__ __forceinline__ void qinv_rot_up(float4 q, float out[3]) {
    float qx = -q.x, qy = -q.y, qz = -q.z, qw = q.w;
    // t = 2*cross(qv, v), v=(0,1,0) -> t = 2*(-qz, 0, qx)
    float tx = -2.f*qz;
    float ty = 0.f;
    float tz = 2.f*qx;
    out[0] = 0.f + qw*tx + (qy*tz - qz*ty);
    out[1] = 1.f + qw*ty + (qz*tx - qx*tz);
    out[2] = 0.f + qw*tz + (qx*ty - qy*tx);
}

// ---------------- kernel 1: exclusive scan of counts + zero d_out --------------
__global__ void scan_zero_kernel(const int* __restrict__ counts,
                                 int* __restrict__ starts,
                                 float* __restrict__ out, int E) {
    __shared__ int lds[1024];
    int tid = threadIdx.x;
    if (tid < 5) out[tid] = 0.0f;
    int base = tid * 4;
    int c0 = (base + 0 < E) ? counts[base + 0] : 0;
    int c1 = (base + 1 < E) ? counts[base + 1] : 0;
    int c2 = (base + 2 < E) ? counts[base + 2] : 0;
    int c3 = (base + 3 < E) ? counts[base + 3] : 0;
    lds[tid] = c0 + c1 + c2 + c3;
    __syncthreads();
    for (int off = 1; off < 1024; off <<= 1) {
        int v = lds[tid];
        int a = (tid >= off) ? lds[tid - off] : 0;
        __syncthreads();
        lds[tid] = v + a;
        __syncthreads();
    }
    int excl = (tid > 0) ? lds[tid - 1] : 0;
    if (base + 0 < E) starts[base + 0] = excl; excl += c0;
    if (base + 1 < E) starts[base + 1] = excl; excl += c1;
    if (base + 2 < E) starts[base + 2] = excl; excl += c2;
    if (base + 3 < E) starts[base + 3] = excl;
}

// ---------------- kernel 2: per-segment sufficient statistics ------------------
// acc layout per segment (32-slot row):
// 0-2 sum_p, 3-5 sum_g, 6 sum|p|^2, 7 sum|g|^2, 8-16 H_raw (row-major),
// 17-26 M upper triangle (xx,xy,xz,xw,yy,yz,yw,zz,zw,ww),
// 27 sum(1-cos_grav), 28 sum(1-dot_deg^2)
__global__ __launch_bounds__(256) void pass1_kernel(
    const float* __restrict__ pred_t, const float4* __restrict__ pred_q,
    const float* __restrict__ gt_t,   const float4* __restrict__ gt_q,
    const int* __restrict__ counts, const int* __restrict__ starts,
    float* __restrict__ segacc)
{
    int e = blockIdx.x;
    int start = starts[e];
    int c = counts[e];
    float4 q0p = pred_q[start];
    float4 q0g = gt_q[start];
    float4 q0pi = make_float4(-q0p.x, -q0p.y, -q0p.z, q0p.w);
    float4 q0gi = make_float4(-q0g.x, -q0g.y, -q0g.z, q0g.w);

    float acc[NACC];
    #pragma unroll
    for (int k = 0; k < NACC; ++k) acc[k] = 0.f;

    for (int i = threadIdx.x; i < c; i += 256) {
        int n = start + i;
        float px = pred_t[3*n+0], py = pred_t[3*n+1], pz = pred_t[3*n+2];
        float gx = gt_t[3*n+0],  gy = gt_t[3*n+1],  gz = gt_t[3*n+2];
        float4 pq = pred_q[n];
        float4 gq = gt_q[n];

        acc[0] += px; acc[1] += py; acc[2] += pz;
        acc[3] += gx; acc[4] += gy; acc[5] += gz;
        acc[6] += px*px + py*py + pz*pz;
        acc[7] += gx*gx + gy*gy + gz*gz;
        acc[8]  += px*gx; acc[9]  += px*gy; acc[10] += px*gz;
        acc[11] += py*gx; acc[12] += py*gy; acc[13] += py*gz;
        acc[14] += pz*gx; acc[15] += pz*gy; acc[16] += pz*gz;

        // m_i = d(dot)/d(q_align_i) where dot = <q_mul(q_align, pq), gq>
        float mx =  pq.w*gq.x - pq.z*gq.y + pq.y*gq.z - pq.x*gq.w;
        float my =  pq.z*gq.x + pq.w*gq.y - pq.x*gq.z - pq.y*gq.w;
        float mz = -pq.y*gq.x + pq.x*gq.y + pq.w*gq.z - pq.z*gq.w;
        float mw =  pq.x*gq.x + pq.y*gq.y + pq.z*gq.z + pq.w*gq.w;
        acc[17] += mx*mx; acc[18] += mx*my; acc[19] += mx*mz; acc[20] += mx*mw;
        acc[21] += my*my; acc[22] += my*mz; acc[23] += my*mw;
        acc[24] += mz*mz; acc[25] += mz*mw; acc[26] += mw*mw;

        // gravity
        float pu[3], gu[3];
        qinv_rot_up(pq, pu);
        qinv_rot_up(gq, gu);
        float nn = sqrtf(pu[0]*pu[0]+pu[1]*pu[1]+pu[2]*pu[2]) *
                   sqrtf(gu[0]*gu[0]+gu[1]*gu[1]+gu[2]*gu[2]);
        float cosv = (pu[0]*gu[0]+pu[1]*gu[1]+pu[2]*gu[2]) / fmaxf(nn, 1e-8f);
        acc[27] += 1.f - cosv;

        // degenerate-branch rotation dot
        float4 aa = qmul4(q0pi, pq);
        float4 bb = qmul4(q0gi, gq);
        float dd = aa.x*bb.x + aa.y*bb.y + aa.z*bb.z + aa.w*bb.w;
        acc[28] += 1.f - dd*dd;
    }

    // wave-level shuffle reduce (wave64)
    #pragma unroll
    for (int k = 0; k < NACC; ++k) {
        float v = acc[k];
        v += __shfl_down(v, 32);
        v += __shfl_down(v, 16);
        v += __shfl_down(v, 8);
        v += __shfl_down(v, 4);
        v += __shfl_down(v, 2);
        v += __shfl_down(v, 1);
        acc[k] = v;
    }
    __shared__ float red[4][NACC];
    int lane = threadIdx.x & 63;
    int wv = threadIdx.x >> 6;
    if (lane == 0) {
        #pragma unroll
        for (int k = 0; k < NACC; ++k) red[wv][k] = acc[k];
    }
    __syncthreads();
    if (threadIdx.x < NACC) {
        float s = red[0][threadIdx.x] + red[1][threadIdx.x] +
                  red[2][threadIdx.x] + red[3][threadIdx.x];
        segacc[(size_t)e*32 + threadIdx.x] = s;
    }
}

// ---------------- kernel 3: per-segment solve + loss reduction -----------------
__device__ void jacobi3(double A[3][3], double V[3][3]) {
    V[0][0]=1.0; V[0][1]=0.0; V[0][2]=0.0;
    V[1][0]=0.0; V[1][1]=1.0; V[1][2]=0.0;
    V[2][0]=0.0; V[2][1]=0.0; V[2][2]=1.0;
    for (int sweep = 0; sweep < 20; ++sweep) {
        double off = A[0][1]*A[0][1] + A[0][2]*A[0][2] + A[1][2]*A[1][2];
        double dia = A[0][0]*A[0][0] + A[1][1]*A[1][1] + A[2][2]*A[2][2];
        if (off <= 1e-28 * (dia + 1e-300)) break;
        for (int p = 0; p < 2; ++p) for (int q = p + 1; q < 3; ++q) {
            double apq = A[p][q];
            if (fabs(apq) < 1e-300) continue;
            double theta = (A[q][q] - A[p][p]) / (2.0 * apq);
            double t = ((theta >= 0.0) ? 1.0 : -1.0) / (fabs(theta) + sqrt(theta*theta + 1.0));
            double cc = 1.0 / sqrt(t*t + 1.0);
            double ss = t * cc;
            double app = A[p][p], aqq = A[q][q];
            A[p][p] = app - t * apq;
            A[q][q] = aqq + t * apq;
            A[p][q] = 0.0; A[q][p] = 0.0;
            int r = 3 - p - q;
            double arp = A[r][p], arq = A[r][q];
            A[r][p] = cc*arp - ss*arq; A[p][r] = A[r][p];
            A[r][q] = ss*arp + cc*arq; A[q][r] = A[r][q];
            for (int i = 0; i < 3; ++i) {
                double vip = V[i][p], viq = V[i][q];
                V[i][p] = cc*vip - ss*viq;
                V[i][q] = ss*vip + cc*viq;
            }
        }
    }
}

__device__ void mat2quat(const double R[3][3], double q[4]) {
    const double eps = 1e-12;
    double tr = R[0][0] + R[1][1] + R[2][2];
    if (tr > 0.0) {
        double S = sqrt(fmax(tr + 1.0, eps)) * 2.0;
        q[0] = (R[2][1]-R[1][2])/S; q[1] = (R[0][2]-R[2][0])/S;
        q[2] = (R[1][0]-R[0][1])/S; q[3] = 0.25*S;
    } else if ((R[0][0] > R[1][1]) && (R[0][0] > R[2][2])) {
        double S = sqrt(fmax(1.0 + R[0][0] - R[1][1] - R[2][2], eps)) * 2.0;
        q[0] = 0.25*S; q[1] = (R[0][1]+R[1][0])/S;
        q[2] = (R[0][2]+R[2][0])/S; q[3] = (R[2][1]-R[1][2])/S;
    } else if (R[1][1] > R[2][2]) {
        double S = sqrt(fmax(1.0 + R[1][1] - R[0][0] - R[2][2], eps)) * 2.0;
        q[0] = (R[0][1]+R[1][0])/S; q[1] = 0.25*S;
        q[2] = (R[1][2]+R[2][1])/S; q[3] = (R[0][2]-R[2][0])/S;
    } else {
        double S = sqrt(fmax(1.0 + R[2][2] - R[0][0] - R[1][1], eps)) * 2.0;
        q[0] = (R[0][2]+R[2][0])/S; q[1] = (R[1][2]+R[2][1])/S;
        q[2] = 0.25*S; q[3] = (R[1][0]-R[0][1])/S;
    }
}

__global__ __launch_bounds__(256) void finalize_kernel(
    const float* __restrict__ segacc, const int* __restrict__ counts,
    const int* __restrict__ starts, const float* __restrict__ pred_t,
    float* __restrict__ out, int E)
{
    int e = blockIdx.x * 256 + threadIdx.x;
    double v_trans = 0.0, v_rot = 0.0, v_grav = 0.0, v_leash = 0.0, v_scale = 0.0;
    if (e < E) {
        const float* A = segacc + (size_t)e * 32;
        int ci = counts[e];
        double c = (double)ci;
        double mu_p[3] = { A[0]/c, A[1]/c, A[2]/c };
        double mu_g[3] = { A[3]/c, A[4]/c, A[5]/c };
        double pp_c = (double)A[6] - c*(mu_p[0]*mu_p[0]+mu_p[1]*mu_p[1]+mu_p[2]*mu_p[2]);
        double gg_c = (double)A[7] - c*(mu_g[0]*mu_g[0]+mu_g[1]*mu_g[1]+mu_g[2]*mu_g[2]);
        double H[3][3];
        H[0][0]=(double)A[8] -c*mu_p[0]*mu_g[0]; H[0][1]=(double)A[9] -c*mu_p[0]*mu_g[1]; H[0][2]=(double)A[10]-c*mu_p[0]*mu_g[2];
        H[1][0]=(double)A[11]-c*mu_p[1]*mu_g[0]; H[1][1]=(double)A[12]-c*mu_p[1]*mu_g[1]; H[1][2]=(double)A[13]-c*mu_p[1]*mu_g[2];
        H[2][0]=(double)A[14]-c*mu_p[2]*mu_g[0]; H[2][1]=(double)A[15]-c*mu_p[2]*mu_g[1]; H[2][2]=(double)A[16]-c*mu_p[2]*mu_g[2];
        double g_var = gg_c / (c - 1.0);
        bool deg = (ci < 4) || (g_var < 1e-4);
        double trH = H[0][0] + H[1][1] + H[2][2];
        double trans, rot, scale = 0.0;
        if (deg) {
            trans = (pp_c - 2.0*trH + gg_c) / (c * 3.0);
            rot = (double)A[28] / c;
        } else {
            // eigendecomp of B = H^T H -> V (columns = eigvecs)
            double B[3][3], V[3][3];
            for (int i = 0; i < 3; ++i)
                for (int j = 0; j < 3; ++j)
                    B[i][j] = H[0][i]*H[0][j] + H[1][i]*H[1][j] + H[2][i]*H[2][j];
            jacobi3(B, V);
            double lam[3] = { B[0][0], B[1][1], B[2][2] };
            int idx[3] = {0, 1, 2};
            if (lam[idx[0]] < lam[idx[1]]) { int t = idx[0]; idx[0] = idx[1]; idx[1] = t; }
            if (lam[idx[0]] < lam[idx[2]]) { int t = idx[0]; idx[0] = idx[2]; idx[2] = t; }
            if (lam[idx[1]] < lam[idx[2]]) { int t = idx[1]; idx[1] = idx[2]; idx[2] = t; }
            double v1[3], v2[3], v3[3];
            for (int i = 0; i < 3; ++i) { v1[i] = V[i][idx[0]]; v2[i] = V[i][idx[1]]; v3[i] = V[i][idx[2]]; }
            // det(V) (sign): triple product v1 . (v2 x v3)
            double detV = v1[0]*(v2[1]*v3[2]-v2[2]*v3[1])
                        - v1[1]*(v2[0]*v3[2]-v2[2]*v3[0])
                        + v1[2]*(v2[0]*v3[1]-v2[1]*v3[0]);
            double sgnV = (detV < 0.0) ? -1.0 : 1.0;
            // U columns: u1 = norm(H v1), u2 = GS(H v2), u3 = u1 x u2
            double u1[3], u2[3], u3[3];
            for (int i = 0; i < 3; ++i) u1[i] = H[i][0]*v1[0] + H[i][1]*v1[1] + H[i][2]*v1[2];
            double n1 = sqrt(u1[0]*u1[0]+u1[1]*u1[1]+u1[2]*u1[2]);
            n1 = fmax(n1, 1e-30);
            for (int i = 0; i < 3; ++i) u1[i] /= n1;
            for (int i = 0; i < 3; ++i) u2[i] = H[i][0]*v2[0] + H[i][1]*v2[1] + H[i][2]*v2[2];
            double d12 = u1[0]*u2[0]+u1[1]*u2[1]+u1[2]*u2[2];
            for (int i = 0; i < 3; ++i) u2[i] -= d12*u1[i];
            double n2 = sqrt(u2[0]*u2[0]+u2[1]*u2[1]+u2[2]*u2[2]);
            n2 = fmax(n2, 1e-30);
            for (int i = 0; i < 3; ++i) u2[i] /= n2;
            u3[0] = u1[1]*u2[2] - u1[2]*u2[1];
            u3[1] = u1[2]*u2[0] - u1[0]*u2[2];
            u3[2] = u1[0]*u2[1] - u1[1]*u2[0];
            // R = v1 u1^T + v2 u2^T + sgnV * v3 u3^T  (== reference V diag(1,1,sgn) U^T)
            double R[3][3];
            for (int i = 0; i < 3; ++i)
                for (int k = 0; k < 3; ++k)
                    R[i][k] = v1[i]*u1[k] + v2[i]*u2[k] + sgnV*v3[i]*u3[k];
            // nom = tr(R H) = sum_{k,j} R[k][j] H[j][k]
            double nom = 0.0;
            for (int k = 0; k < 3; ++k)
                for (int j = 0; j < 3; ++j)
                    nom += R[k][j] * H[j][k];
            double denom = pp_c;
            double s = 1.0;
            if (denom > 1e-6) {
                s = nom / fmax(denom, 1e-6);
                s = fmin(fmax(s, 1e-3), 1e3);
            }
            trans = (s*s*denom - 2.0*s*nom + gg_c) / (c * 3.0);
            double ls = log(fabs(s) + 1e-6);
            scale = ls * ls;
            double q[4];
            mat2quat(R, q);
            double M00=A[17], M01=A[18], M02=A[19], M03=A[20], M11=A[21],
                   M12=A[22], M13=A[23], M22=A[24], M23=A[25], M33=A[26];
            double quad = q[0]*q[0]*M00 + q[1]*q[1]*M11 + q[2]*q[2]*M22 + q[3]*q[3]*M33
                + 2.0*(q[0]*q[1]*M01 + q[0]*q[2]*M02 + q[0]*q[3]*M03
                     + q[1]*q[2]*M12 + q[1]*q[3]*M13 + q[2]*q[3]*M23);
            rot = (c - quad) / c;
        }
        double grav = (double)A[27] / c;
        int st = starts[e];
        double tx = (double)pred_t[3*st+0], ty = (double)pred_t[3*st+1], tz = (double)pred_t[3*st+2];
        double mag = sqrt(tx*tx + ty*ty + tz*tz);
        double ml = fmax(mag - 15.0, 0.0);
        double Ed = (double)E;
        v_trans = trans / Ed;
        v_rot   = rot / Ed;
        v_grav  = grav / Ed;
        v_leash = (ml * ml) / Ed;
        v_scale = scale / Ed;
    }
    // block reduce 5 values, atomicAdd
    __shared__ double sd[256];
    double vals[5] = { v_trans, v_rot, v_grav, v_leash, v_scale };
    for (int k = 0; k < 5; ++k) {
        sd[threadIdx.x] = vals[k];
        __syncthreads();
        for (int off = 128; off > 0; off >>= 1) {
            if (threadIdx.x < off) sd[threadIdx.x] += sd[threadIdx.x + off];
            __syncthreads();
        }
        if (threadIdx.x == 0) atomicAdd(out + k, (float)sd[0]);
        __syncthreads();
    }
}

extern "C" void kernel_launch(void* const* d_in, const int* in_sizes, int n_in,
                              void* d_out, int out_size, void* d_ws, size_t ws_size,
                              hipStream_t stream) {
    const float*  pred_t = (const float*)d_in[0];
    const float4* pred_q = (const float4*)d_in[1];
    const float*  gt_t   = (const float*)d_in[2];
    const float4* gt_q   = (const float4*)d_in[3];
    const int*    counts = (const int*)d_in[4];
    int E = in_sizes[4];

    int* starts = (int*)d_ws;
    size_t off = ((size_t)E * sizeof(int) + 255) & ~(size_t)255;
    float* segacc = (float*)((char*)d_ws + off);

    scan_zero_kernel<<<1, 1024, 0, stream>>>(counts, starts, (float*)d_out, E);
    pass1_kernel<<<E, 256, 0, stream>>>(pred_t, pred_q, gt_t, gt_q, counts, starts, segacc);
    finalize_kernel<<<(E + 255) / 256, 256, 0, stream>>>(segacc, counts, starts, pred_t,
                                                         (float*)d_out, E);
}

// Round 2
// 121.760 us; speedup vs baseline: 1.1426x; 1.1426x over previous
//
#include <hip/hip_runtime.h>
#include <math.h>

#define NACC 29

__device__ __forceinline__ float4 qmul4(float4 a, float4 b) {
    return make_float4(
        a.w*b.x + a.x*b.w + a.y*b.z - a.z*b.y,
        a.w*b.y - a.x*b.z + a.y*b.w + a.z*b.x,
        a.w*b.z + a.x*b.y - a.y*b.x + a.z*b.w,
        a.w*b.w - a.x*b.x - a.y*b.y - a.z*b.z);
}

// rotate v=(0,1,0) by q_inv(q) = (-x,-y,-z,w), reference q_rot formula
__device__ __forceinline__ void qinv_rot_up(float4 q, float out[3]) {
    float qx = -q.x, qy = -q.y, qz = -q.z, qw = q.w;
    float tx = -2.f*qz;
    float ty = 0.f;
    float tz = 2.f*qx;
    out[0] = 0.f + qw*tx + (qy*tz - qz*ty);
    out[1] = 1.f + qw*ty + (qz*tx - qx*tz);
    out[2] = 0.f + qw*tz + (qx*ty - qy*tx);
}

// ---------------- kernel 1: exclusive scan of counts + zero d_out --------------
__global__ void scan_zero_kernel(const int* __restrict__ counts,
                                 int* __restrict__ starts,
                                 float* __restrict__ out, int E) {
    __shared__ int lds[1024];
    int tid = threadIdx.x;
    if (tid < 5) out[tid] = 0.0f;
    int base = tid * 4;
    int c0 = (base + 0 < E) ? counts[base + 0] : 0;
    int c1 = (base + 1 < E) ? counts[base + 1] : 0;
    int c2 = (base + 2 < E) ? counts[base + 2] : 0;
    int c3 = (base + 3 < E) ? counts[base + 3] : 0;
    lds[tid] = c0 + c1 + c2 + c3;
    __syncthreads();
    for (int off = 1; off < 1024; off <<= 1) {
        int v = lds[tid];
        int a = (tid >= off) ? lds[tid - off] : 0;
        __syncthreads();
        lds[tid] = v + a;
        __syncthreads();
    }
    int excl = (tid > 0) ? lds[tid - 1] : 0;
    if (base + 0 < E) starts[base + 0] = excl; excl += c0;
    if (base + 1 < E) starts[base + 1] = excl; excl += c1;
    if (base + 2 < E) starts[base + 2] = excl; excl += c2;
    if (base + 3 < E) starts[base + 3] = excl;
}

// ---------------- kernel 2: per-segment sufficient statistics ------------------
// ONE WAVE (64 threads) per segment: avg ~4 points/lane, one 29x6 xor-butterfly
// per segment (was 4 waves + cross-wave LDS stage).
// acc layout per segment (32-slot row):
// 0-2 sum_p, 3-5 sum_g, 6 sum|p|^2, 7 sum|g|^2, 8-16 H_raw (row-major),
// 17-26 M upper triangle (xx,xy,xz,xw,yy,yz,yw,zz,zw,ww),
// 27 sum(1-cos_grav), 28 sum(1-dot_deg^2)
__global__ __launch_bounds__(64) void pass1_kernel(
    const float* __restrict__ pred_t, const float4* __restrict__ pred_q,
    const float* __restrict__ gt_t,   const float4* __restrict__ gt_q,
    const int* __restrict__ counts, const int* __restrict__ starts,
    float* __restrict__ segacc)
{
    int e = blockIdx.x;
    int start = starts[e];
    int c = counts[e];
    float4 q0p = pred_q[start];
    float4 q0g = gt_q[start];
    float4 q0pi = make_float4(-q0p.x, -q0p.y, -q0p.z, q0p.w);
    float4 q0gi = make_float4(-q0g.x, -q0g.y, -q0g.z, q0g.w);

    float acc[NACC];
    #pragma unroll
    for (int k = 0; k < NACC; ++k) acc[k] = 0.f;

    for (int i = threadIdx.x; i < c; i += 64) {
        int n = start + i;
        float px = pred_t[3*n+0], py = pred_t[3*n+1], pz = pred_t[3*n+2];
        float gx = gt_t[3*n+0],  gy = gt_t[3*n+1],  gz = gt_t[3*n+2];
        float4 pq = pred_q[n];
        float4 gq = gt_q[n];

        acc[0] += px; acc[1] += py; acc[2] += pz;
        acc[3] += gx; acc[4] += gy; acc[5] += gz;
        acc[6] += px*px + py*py + pz*pz;
        acc[7] += gx*gx + gy*gy + gz*gz;
        acc[8]  += px*gx; acc[9]  += px*gy; acc[10] += px*gz;
        acc[11] += py*gx; acc[12] += py*gy; acc[13] += py*gz;
        acc[14] += pz*gx; acc[15] += pz*gy; acc[16] += pz*gz;

        // m_i = d(dot)/d(q_align_i) where dot = <q_mul(q_align, pq), gq>
        float mx =  pq.w*gq.x - pq.z*gq.y + pq.y*gq.z - pq.x*gq.w;
        float my =  pq.z*gq.x + pq.w*gq.y - pq.x*gq.z - pq.y*gq.w;
        float mz = -pq.y*gq.x + pq.x*gq.y + pq.w*gq.z - pq.z*gq.w;
        float mw =  pq.x*gq.x + pq.y*gq.y + pq.z*gq.z + pq.w*gq.w;
        acc[17] += mx*mx; acc[18] += mx*my; acc[19] += mx*mz; acc[20] += mx*mw;
        acc[21] += my*my; acc[22] += my*mz; acc[23] += my*mw;
        acc[24] += mz*mz; acc[25] += mz*mw; acc[26] += mw*mw;

        // gravity
        float pu[3], gu[3];
        qinv_rot_up(pq, pu);
        qinv_rot_up(gq, gu);
        float nn = sqrtf(pu[0]*pu[0]+pu[1]*pu[1]+pu[2]*pu[2]) *
                   sqrtf(gu[0]*gu[0]+gu[1]*gu[1]+gu[2]*gu[2]);
        float cosv = (pu[0]*gu[0]+pu[1]*gu[1]+pu[2]*gu[2]) / fmaxf(nn, 1e-8f);
        acc[27] += 1.f - cosv;

        // degenerate-branch rotation dot
        float4 aa = qmul4(q0pi, pq);
        float4 bb = qmul4(q0gi, gq);
        float dd = aa.x*bb.x + aa.y*bb.y + aa.z*bb.z + aa.w*bb.w;
        acc[28] += 1.f - dd*dd;
    }

    // xor-butterfly: every lane ends with the full sum
    #pragma unroll
    for (int k = 0; k < NACC; ++k) {
        float v = acc[k];
        v += __shfl_xor(v, 32);
        v += __shfl_xor(v, 16);
        v += __shfl_xor(v, 8);
        v += __shfl_xor(v, 4);
        v += __shfl_xor(v, 2);
        v += __shfl_xor(v, 1);
        acc[k] = v;
    }
    // lane k stores acc[k] -> one coalesced 116B store per segment
    float outv = 0.f;
    #pragma unroll
    for (int k = 0; k < NACC; ++k)
        if ((int)threadIdx.x == k) outv = acc[k];
    if (threadIdx.x < NACC)
        segacc[(size_t)e*32 + threadIdx.x] = outv;
}

// ---------------- kernel 3: per-segment solve + loss reduction (fp32) ----------
__device__ void jacobi3f(float A[3][3], float V[3][3]) {
    V[0][0]=1.f; V[0][1]=0.f; V[0][2]=0.f;
    V[1][0]=0.f; V[1][1]=1.f; V[1][2]=0.f;
    V[2][0]=0.f; V[2][1]=0.f; V[2][2]=1.f;
    for (int sweep = 0; sweep < 6; ++sweep) {
        float off = A[0][1]*A[0][1] + A[0][2]*A[0][2] + A[1][2]*A[1][2];
        float dia = A[0][0]*A[0][0] + A[1][1]*A[1][1] + A[2][2]*A[2][2];
        if (off <= 1e-12f * (dia + 1e-30f)) break;
        for (int p = 0; p < 2; ++p) for (int q = p + 1; q < 3; ++q) {
            float apq = A[p][q];
            if (fabsf(apq) < 1e-30f) continue;
            float theta = (A[q][q] - A[p][p]) / (2.0f * apq);
            float t = ((theta >= 0.f) ? 1.f : -1.f) / (fabsf(theta) + sqrtf(theta*theta + 1.f));
            float cc = 1.f / sqrtf(t*t + 1.f);
            float ss = t * cc;
            float app = A[p][p], aqq = A[q][q];
            A[p][p] = app - t * apq;
            A[q][q] = aqq + t * apq;
            A[p][q] = 0.f; A[q][p] = 0.f;
            int r = 3 - p - q;
            float arp = A[r][p], arq = A[r][q];
            A[r][p] = cc*arp - ss*arq; A[p][r] = A[r][p];
            A[r][q] = ss*arp + cc*arq; A[q][r] = A[r][q];
            for (int i = 0; i < 3; ++i) {
                float vip = V[i][p], viq = V[i][q];
                V[i][p] = cc*vip - ss*viq;
                V[i][q] = ss*vip + cc*viq;
            }
        }
    }
}

__device__ void mat2quatf(const float R[3][3], float q[4]) {
    const float eps = 1e-12f;
    float tr = R[0][0] + R[1][1] + R[2][2];
    if (tr > 0.f) {
        float S = sqrtf(fmaxf(tr + 1.f, eps)) * 2.f;
        q[0] = (R[2][1]-R[1][2])/S; q[1] = (R[0][2]-R[2][0])/S;
        q[2] = (R[1][0]-R[0][1])/S; q[3] = 0.25f*S;
    } else if ((R[0][0] > R[1][1]) && (R[0][0] > R[2][2])) {
        float S = sqrtf(fmaxf(1.f + R[0][0] - R[1][1] - R[2][2], eps)) * 2.f;
        q[0] = 0.25f*S; q[1] = (R[0][1]+R[1][0])/S;
        q[2] = (R[0][2]+R[2][0])/S; q[3] = (R[2][1]-R[1][2])/S;
    } else if (R[1][1] > R[2][2]) {
        float S = sqrtf(fmaxf(1.f + R[1][1] - R[0][0] - R[2][2], eps)) * 2.f;
        q[0] = (R[0][1]+R[1][0])/S; q[1] = 0.25f*S;
        q[2] = (R[1][2]+R[2][1])/S; q[3] = (R[0][2]-R[2][0])/S;
    } else {
        float S = sqrtf(fmaxf(1.f + R[2][2] - R[0][0] - R[1][1], eps)) * 2.f;
        q[0] = (R[0][2]+R[2][0])/S; q[1] = (R[1][2]+R[2][1])/S;
        q[2] = 0.25f*S; q[3] = (R[1][0]-R[0][1])/S;
    }
}

__global__ __launch_bounds__(64) void finalize_kernel(
    const float* __restrict__ segacc, const int* __restrict__ counts,
    const int* __restrict__ starts, const float* __restrict__ pred_t,
    float* __restrict__ out, int E)
{
    int e = blockIdx.x * 64 + threadIdx.x;
    float v_trans = 0.f, v_rot = 0.f, v_grav = 0.f, v_leash = 0.f, v_scale = 0.f;
    if (e < E) {
        const float* A = segacc + (size_t)e * 32;
        int ci = counts[e];
        float c = (float)ci;
        float mu_p[3] = { A[0]/c, A[1]/c, A[2]/c };
        float mu_g[3] = { A[3]/c, A[4]/c, A[5]/c };
        float pp_c = A[6] - c*(mu_p[0]*mu_p[0]+mu_p[1]*mu_p[1]+mu_p[2]*mu_p[2]);
        float gg_c = A[7] - c*(mu_g[0]*mu_g[0]+mu_g[1]*mu_g[1]+mu_g[2]*mu_g[2]);
        float H[3][3];
        H[0][0]=A[8] -c*mu_p[0]*mu_g[0]; H[0][1]=A[9] -c*mu_p[0]*mu_g[1]; H[0][2]=A[10]-c*mu_p[0]*mu_g[2];
        H[1][0]=A[11]-c*mu_p[1]*mu_g[0]; H[1][1]=A[12]-c*mu_p[1]*mu_g[1]; H[1][2]=A[13]-c*mu_p[1]*mu_g[2];
        H[2][0]=A[14]-c*mu_p[2]*mu_g[0]; H[2][1]=A[15]-c*mu_p[2]*mu_g[1]; H[2][2]=A[16]-c*mu_p[2]*mu_g[2];
        float g_var = gg_c / (c - 1.0f);
        bool deg = (ci < 4) || (g_var < 1e-4f);
        float trH = H[0][0] + H[1][1] + H[2][2];
        float trans, rot, scale = 0.f;
        if (deg) {
            trans = (pp_c - 2.f*trH + gg_c) / (c * 3.f);
            rot = A[28] / c;
        } else {
            // eigendecomp of B = H^T H -> V (columns = eigvecs)
            float B[3][3], V[3][3];
            for (int i = 0; i < 3; ++i)
                for (int j = 0; j < 3; ++j)
                    B[i][j] = H[0][i]*H[0][j] + H[1][i]*H[1][j] + H[2][i]*H[2][j];
            jacobi3f(B, V);
            float lam[3] = { B[0][0], B[1][1], B[2][2] };
            int idx[3] = {0, 1, 2};
            if (lam[idx[0]] < lam[idx[1]]) { int t = idx[0]; idx[0] = idx[1]; idx[1] = t; }
            if (lam[idx[0]] < lam[idx[2]]) { int t = idx[0]; idx[0] = idx[2]; idx[2] = t; }
            if (lam[idx[1]] < lam[idx[2]]) { int t = idx[1]; idx[1] = idx[2]; idx[2] = t; }
            float v1[3], v2[3], v3[3];
            for (int i = 0; i < 3; ++i) { v1[i] = V[i][idx[0]]; v2[i] = V[i][idx[1]]; v3[i] = V[i][idx[2]]; }
            float detV = v1[0]*(v2[1]*v3[2]-v2[2]*v3[1])
                       - v1[1]*(v2[0]*v3[2]-v2[2]*v3[0])
                       + v1[2]*(v2[0]*v3[1]-v2[1]*v3[0]);
            float sgnV = (detV < 0.f) ? -1.f : 1.f;
            // U columns: u1 = norm(H v1), u2 = GS(H v2), u3 = u1 x u2
            float u1[3], u2[3], u3[3];
            for (int i = 0; i < 3; ++i) u1[i] = H[i][0]*v1[0] + H[i][1]*v1[1] + H[i][2]*v1[2];
            float n1 = sqrtf(u1[0]*u1[0]+u1[1]*u1[1]+u1[2]*u1[2]);
            n1 = fmaxf(n1, 1e-30f);
            for (int i = 0; i < 3; ++i) u1[i] /= n1;
            for (int i = 0; i < 3; ++i) u2[i] = H[i][0]*v2[0] + H[i][1]*v2[1] + H[i][2]*v2[2];
            float d12 = u1[0]*u2[0]+u1[1]*u2[1]+u1[2]*u2[2];
            for (int i = 0; i < 3; ++i) u2[i] -= d12*u1[i];
            float n2 = sqrtf(u2[0]*u2[0]+u2[1]*u2[1]+u2[2]*u2[2]);
            n2 = fmaxf(n2, 1e-30f);
            for (int i = 0; i < 3; ++i) u2[i] /= n2;
            u3[0] = u1[1]*u2[2] - u1[2]*u2[1];
            u3[1] = u1[2]*u2[0] - u1[0]*u2[2];
            u3[2] = u1[0]*u2[1] - u1[1]*u2[0];
            // R = v1 u1^T + v2 u2^T + sgnV * v3 u3^T  (== reference V diag(1,1,sgn) U^T)
            float R[3][3];
            for (int i = 0; i < 3; ++i)
                for (int k = 0; k < 3; ++k)
                    R[i][k] = v1[i]*u1[k] + v2[i]*u2[k] + sgnV*v3[i]*u3[k];
            // nom = tr(R H)
            float nom = 0.f;
            for (int k = 0; k < 3; ++k)
                for (int j = 0; j < 3; ++j)
                    nom += R[k][j] * H[j][k];
            float denom = pp_c;
            float s = 1.f;
            if (denom > 1e-6f) {
                s = nom / fmaxf(denom, 1e-6f);
                s = fminf(fmaxf(s, 1e-3f), 1e3f);
            }
            trans = (s*s*denom - 2.f*s*nom + gg_c) / (c * 3.f);
            float ls = logf(fabsf(s) + 1e-6f);
            scale = ls * ls;
            float q[4];
            mat2quatf(R, q);
            float M00=A[17], M01=A[18], M02=A[19], M03=A[20], M11=A[21],
                  M12=A[22], M13=A[23], M22=A[24], M23=A[25], M33=A[26];
            float quad = q[0]*q[0]*M00 + q[1]*q[1]*M11 + q[2]*q[2]*M22 + q[3]*q[3]*M33
                + 2.f*(q[0]*q[1]*M01 + q[0]*q[2]*M02 + q[0]*q[3]*M03
                     + q[1]*q[2]*M12 + q[1]*q[3]*M13 + q[2]*q[3]*M23);
            rot = (c - quad) / c;
        }
        float grav = A[27] / c;
        int st = starts[e];
        float tx = pred_t[3*st+0], ty = pred_t[3*st+1], tz = pred_t[3*st+2];
        float mag = sqrtf(tx*tx + ty*ty + tz*tz);
        float ml = fmaxf(mag - 15.f, 0.f);
        float Ed = (float)E;
        v_trans = trans / Ed;
        v_rot   = rot / Ed;
        v_grav  = grav / Ed;
        v_leash = (ml * ml) / Ed;
        v_scale = scale / Ed;
    }
    // wave-level reduce, one atomic per block per loss
    float vals[5] = { v_trans, v_rot, v_grav, v_leash, v_scale };
    #pragma unroll
    for (int k = 0; k < 5; ++k) {
        float v = vals[k];
        v += __shfl_down(v, 32);
        v += __shfl_down(v, 16);
        v += __shfl_down(v, 8);
        v += __shfl_down(v, 4);
        v += __shfl_down(v, 2);
        v += __shfl_down(v, 1);
        if (threadIdx.x == 0) atomicAdd(out + k, v);
    }
}

extern "C" void kernel_launch(void* const* d_in, const int* in_sizes, int n_in,
                              void* d_out, int out_size, void* d_ws, size_t ws_size,
                              hipStream_t stream) {
    const float*  pred_t = (const float*)d_in[0];
    const float4* pred_q = (const float4*)d_in[1];
    const float*  gt_t   = (const float*)d_in[2];
    const float4* gt_q   = (const float4*)d_in[3];
    const int*    counts = (const int*)d_in[4];
    int E = in_sizes[4];

    int* starts = (int*)d_ws;
    size_t off = ((size_t)E * sizeof(int) + 255) & ~(size_t)255;
    float* segacc = (float*)((char*)d_ws + off);

    scan_zero_kernel<<<1, 1024, 0, stream>>>(counts, starts, (float*)d_out, E);
    pass1_kernel<<<E, 64, 0, stream>>>(pred_t, pred_q, gt_t, gt_q, counts, starts, segacc);
    finalize_kernel<<<(E + 63) / 64, 64, 0, stream>>>(segacc, counts, starts, pred_t,
                                                      (float*)d_out, E);
}